// Round 7
// baseline (4733.981 us; speedup 1.0000x reference)
//
#include <hip/hip_runtime.h>
#include <cmath>

#define DIM 16
#define VOCAB 18
#define TLEN 2048

// Load float input element idx, from either a bf16 or f32 device buffer.
__device__ __forceinline__ float ldf(const void* p, int idx, int isbf) {
    if (isbf) {
        unsigned int w = ((const unsigned short*)p)[idx];
        return __uint_as_float(w << 16);
    }
    return ((const float*)p)[idx];
}

// ---------------------------------------------------------------------------
// Detector 1: token width. int64 tokens (0..17) have all odd 32-bit words 0.
// flag[0] <- 1 if int64, 0 if int32.
// ---------------------------------------------------------------------------
__global__ void detect_tok(const int* __restrict__ x32, int* __restrict__ flag) {
    int v = 0;
    for (int j = threadIdx.x; j < 4096; j += 64) v |= x32[2 * j + 1];
    unsigned long long any = __ballot(v != 0);
    if (threadIdx.x == 0) flag[0] = (any == 0ULL) ? 1 : 0;
}

// ---------------------------------------------------------------------------
// Detector 2: float width. bf16 words of N(0,1) data have exponent in
// [90,140]; f32 lo-mantissa words are uniform random -> certain failure.
// flag[1] <- 1 if bf16, 0 if f32.
// ---------------------------------------------------------------------------
__global__ void detect_f(const unsigned short* __restrict__ emb16,
                         int* __restrict__ flag) {
    int bad = 0;
    for (int j = threadIdx.x; j < VOCAB * DIM; j += 64) {
        unsigned short w = emb16[j];
        int e = (w >> 7) & 0xFF;
        if (!((e >= 90 && e <= 140) || (w & 0x7FFF) == 0)) bad = 1;
    }
    unsigned long long anybad = __ballot(bad);
    if (threadIdx.x == 0) flag[1] = (anybad == 0ULL) ? 1 : 0;
}

// ---------------------------------------------------------------------------
// Setup: wtab[v][k] = sum_d emb[v,d] * W_w[k,d] + W_b[k]   (18 x 16, f32)
// ---------------------------------------------------------------------------
__global__ void wtab_kernel(const void* __restrict__ emb,
                            const void* __restrict__ W_w,
                            const void* __restrict__ W_b,
                            const int* __restrict__ flag,
                            float* __restrict__ wtab) {
    int tid = threadIdx.x;
    int isbf = flag[1];
    if (tid < VOCAB * DIM) {
        int v = tid >> 4, kk = tid & 15;
        float s = ldf(W_b, kk, isbf);
#pragma unroll
        for (int d = 0; d < DIM; ++d)
            s = fmaf(ldf(emb, v * DIM + d, isbf), ldf(W_w, kk * DIM + d, isbf), s);
        wtab[tid] = s;
    }
}

// ---------------------------------------------------------------------------
// Scalar-correct kernel: one thread per batch row, f32 output stores.
// ---------------------------------------------------------------------------
__global__ __launch_bounds__(64) void rnn_scalar(const int* __restrict__ x32,
                                                 const int* __restrict__ flag,
                                                 const float* __restrict__ wtab_g,
                                                 const void* __restrict__ U_w,
                                                 const void* __restrict__ head_w,
                                                 const void* __restrict__ head_b,
                                                 float* __restrict__ out) {
    __shared__ float sU[DIM * DIM];     // U[k][d]
    __shared__ float swt[DIM * VOCAB];  // wtab transposed: [k][v]

    const int tid = threadIdx.x;
    const int is64 = flag[0];
    const int isbf = flag[1];

    for (int i = tid; i < DIM * DIM; i += 64) sU[i] = ldf(U_w, i, isbf);
    for (int i = tid; i < VOCAB * DIM; i += 64) {
        int v = i >> 4, k = i & 15;
        swt[k * VOCAB + v] = wtab_g[i];
    }
    __syncthreads();

    const int elem = blockIdx.x * 64 + tid;
    const size_t base = (size_t)elem * TLEN;

    float h[DIM];
#pragma unroll
    for (int d = 0; d < DIM; ++d) h[d] = 0.0f;

    for (int t = 0; t < TLEN; ++t) {
        int tok = is64 ? x32[(base + t) << 1] : x32[base + t];
        float hn[DIM];
#pragma unroll
        for (int k = 0; k < DIM; ++k) {
            float a = swt[k * VOCAB + tok];
#pragma unroll
            for (int d = 0; d < DIM; ++d)
                a = fmaf(sU[k * DIM + d], h[d], a);
            hn[k] = tanhf(a);
        }
#pragma unroll
        for (int k = 0; k < DIM; ++k) h[k] = hn[k];
    }

    // Head: out[elem, v] = h . head_w[v,:] + head_b[v], f32 store.
#pragma unroll
    for (int v = 0; v < VOCAB; ++v) {
        float s = ldf(head_b, v, isbf);
#pragma unroll
        for (int d = 0; d < DIM; ++d)
            s = fmaf(h[d], ldf(head_w, v * DIM + d, isbf), s);
        out[(size_t)elem * VOCAB + v] = s;
    }
}

extern "C" void kernel_launch(void* const* d_in, const int* in_sizes, int n_in,
                              void* d_out, int out_size, void* d_ws, size_t ws_size,
                              hipStream_t stream) {
    const int* x = (const int*)d_in[0];
    const void* emb = d_in[1];
    const void* W_w = d_in[2];
    const void* W_b = d_in[3];
    const void* U_w = d_in[4];
    const void* head_w = d_in[5];
    const void* head_b = d_in[6];

    float* wtab = (float*)d_ws;              // 288 floats
    int* flag = (int*)((char*)d_ws + 4096);  // [0]=tok is64, [1]=floats are bf16

    detect_tok<<<1, 64, 0, stream>>>(x, flag);
    detect_f<<<1, 64, 0, stream>>>((const unsigned short*)emb, flag);
    wtab_kernel<<<1, 320, 0, stream>>>(emb, W_w, W_b, flag, wtab);
    rnn_scalar<<<64, 64, 0, stream>>>(x, flag, wtab, U_w, head_w, head_b,
                                      (float*)d_out);
}

// Round 11
// 451.080 us; speedup vs baseline: 10.4948x; 10.4948x over previous
//
#include <hip/hip_runtime.h>
#include <cmath>

#define DIM 16
#define VOCAB 18
#define TLEN 2048
#define NBLK (TLEN / 64)

// Load float input element idx, from either a bf16 or f32 device buffer.
__device__ __forceinline__ float ldf(const void* p, int idx, int isbf) {
    if (isbf) {
        unsigned int w = ((const unsigned short*)p)[idx];
        return __uint_as_float(w << 16);
    }
    return ((const float*)p)[idx];
}

// ---------------------------------------------------------------------------
// Detector 1: token width. int64 tokens (0..17) have all odd 32-bit words 0.
// flag[0] <- 1 if int64, 0 if int32.
// ---------------------------------------------------------------------------
__global__ void detect_tok(const int* __restrict__ x32, int* __restrict__ flag) {
    int v = 0;
    for (int j = threadIdx.x; j < 4096; j += 64) v |= x32[2 * j + 1];
    unsigned long long any = __ballot(v != 0);
    if (threadIdx.x == 0) flag[0] = (any == 0ULL) ? 1 : 0;
}

// ---------------------------------------------------------------------------
// Detector 2: float width. bf16 words of N(0,1) data have exponent in
// [90,140]; f32 lo-mantissa words are uniform random -> certain failure.
// flag[1] <- 1 if bf16, 0 if f32.
// ---------------------------------------------------------------------------
__global__ void detect_f(const unsigned short* __restrict__ emb16,
                         int* __restrict__ flag) {
    int bad = 0;
    for (int j = threadIdx.x; j < VOCAB * DIM; j += 64) {
        unsigned short w = emb16[j];
        int e = (w >> 7) & 0xFF;
        if (!((e >= 90 && e <= 140) || (w & 0x7FFF) == 0)) bad = 1;
    }
    unsigned long long anybad = __ballot(bad);
    if (threadIdx.x == 0) flag[1] = (anybad == 0ULL) ? 1 : 0;
}

// ---------------------------------------------------------------------------
// Setup: wtab[v][k] = sum_d emb[v,d] * W_w[k,d] + W_b[k]   (18 x 16, f32)
// ---------------------------------------------------------------------------
__global__ void wtab_kernel(const void* __restrict__ emb,
                            const void* __restrict__ W_w,
                            const void* __restrict__ W_b,
                            const int* __restrict__ flag,
                            float* __restrict__ wtab) {
    int tid = threadIdx.x;
    int isbf = flag[1];
    if (tid < VOCAB * DIM) {
        int v = tid >> 4, kk = tid & 15;
        float s = ldf(W_b, kk, isbf);
#pragma unroll
        for (int d = 0; d < DIM; ++d)
            s = fmaf(ldf(emb, v * DIM + d, isbf), ldf(W_w, kk * DIM + d, isbf), s);
        wtab[tid] = s;
    }
}

// ---------------------------------------------------------------------------
// Main RNN kernel. 16 lanes per batch element (lane k owns output dim k),
// 4 elements per wave, 4 waves per block, 256 blocks -> 4096 elements.
// ---------------------------------------------------------------------------
__global__ __launch_bounds__(256) void rnn_kernel(const int* __restrict__ x32,
                                                  const int* __restrict__ flag,
                                                  const float* __restrict__ wtab_g,
                                                  const void* __restrict__ U_w,
                                                  const void* __restrict__ head_w,
                                                  const void* __restrict__ head_b,
                                                  float* __restrict__ out) {
    __shared__ float lds_wtab[VOCAB * DIM];
    __shared__ float lds_h[16][DIM];
    __shared__ int lds_tok[16][68];  // 68: int4-alignment-preserving bank pad

    const int tid = threadIdx.x;
    // BUG FIX (R2..R10): VOCAB*DIM = 288 > blockDim = 256. The old guarded
    // single store left entries 256..287 (tokens 16,17) as LDS garbage.
    // Strided loop covers all 288 — this was the sole wave-kernel bug.
    for (int i = tid; i < VOCAB * DIM; i += 256) lds_wtab[i] = wtab_g[i];

    const int is64 = __builtin_amdgcn_readfirstlane(flag[0]);
    const int isbf = __builtin_amdgcn_readfirstlane(flag[1]);

    const int lane = tid & 63;
    const int wave = tid >> 6;
    const int sub = lane >> 4;        // element within wave
    const int k = lane & 15;          // output dim owned by this lane
    const int e = (wave << 2) | sub;  // element within block

    // U row k: h_new[k] = tanh(wtab[tok][k] + sum_d U[k][d]*h[d])
    float u[DIM];
#pragma unroll
    for (int d = 0; d < DIM; ++d) u[d] = ldf(U_w, (k << 4) + d, isbf);

    float h = 0.0f;

// One RNN step, token passed directly (group-uniform value from LDS).
#define RSTEP(TOK)                                   \
    {                                                \
        const float* wrow = lds_wtab + ((TOK) << 4); \
        float a0 = wrow[k];                          \
        float a1 = 0.f, a2 = 0.f, a3 = 0.f;          \
        a0 = fmaf(u[0], __shfl(h, 0, 16), a0);       \
        a1 = fmaf(u[1], __shfl(h, 1, 16), a1);       \
        a2 = fmaf(u[2], __shfl(h, 2, 16), a2);       \
        a3 = fmaf(u[3], __shfl(h, 3, 16), a3);       \
        a0 = fmaf(u[4], __shfl(h, 4, 16), a0);       \
        a1 = fmaf(u[5], __shfl(h, 5, 16), a1);       \
        a2 = fmaf(u[6], __shfl(h, 6, 16), a2);       \
        a3 = fmaf(u[7], __shfl(h, 7, 16), a3);       \
        a0 = fmaf(u[8], __shfl(h, 8, 16), a0);       \
        a1 = fmaf(u[9], __shfl(h, 9, 16), a1);       \
        a2 = fmaf(u[10], __shfl(h, 10, 16), a2);     \
        a3 = fmaf(u[11], __shfl(h, 11, 16), a3);     \
        a0 = fmaf(u[12], __shfl(h, 12, 16), a0);     \
        a1 = fmaf(u[13], __shfl(h, 13, 16), a1);     \
        a2 = fmaf(u[14], __shfl(h, 14, 16), a2);     \
        a3 = fmaf(u[15], __shfl(h, 15, 16), a3);     \
        h = tanhf((a0 + a1) + (a2 + a3));            \
    }

    for (int blk = 0; blk < NBLK; ++blk) {
        __syncthreads();  // lds_tok (and, first pass, lds_wtab) safe to (re)fill
        for (int i = tid; i < 1024; i += 256) {
            int ee = i >> 6, s = i & 63;
            size_t idx = (size_t)((blockIdx.x << 4) | ee) * TLEN + (blk << 6) + s;
            lds_tok[ee][s] = is64 ? x32[idx << 1] : x32[idx];  // R7 expression
        }
        __syncthreads();

#pragma unroll
        for (int s4 = 0; s4 < 16; ++s4) {
            int4 tq = *(const int4*)&lds_tok[e][s4 << 2];
            RSTEP(tq.x) RSTEP(tq.y) RSTEP(tq.z) RSTEP(tq.w)
        }
    }

    // Head: out[b,v] = h . head_w[v,:] + head_b[v], f32 store.
    lds_h[e][k] = h;
    __syncthreads();

    for (int i = tid; i < 16 * VOCAB; i += 256) {
        int ee = i / VOCAB;
        int v = i - ee * VOCAB;
        float s = ldf(head_b, v, isbf);
#pragma unroll
        for (int d = 0; d < DIM; ++d)
            s = fmaf(lds_h[ee][d], ldf(head_w, (v << 4) + d, isbf), s);
        out[(size_t)((blockIdx.x << 4) | ee) * VOCAB + v] = s;
    }
}

extern "C" void kernel_launch(void* const* d_in, const int* in_sizes, int n_in,
                              void* d_out, int out_size, void* d_ws, size_t ws_size,
                              hipStream_t stream) {
    const int* x = (const int*)d_in[0];
    const void* emb = d_in[1];
    const void* W_w = d_in[2];
    const void* W_b = d_in[3];
    const void* U_w = d_in[4];
    const void* head_w = d_in[5];
    const void* head_b = d_in[6];

    float* wtab = (float*)d_ws;              // 288 floats
    int* flag = (int*)((char*)d_ws + 4096);  // [0]=tok is64, [1]=floats are bf16

    detect_tok<<<1, 64, 0, stream>>>(x, flag);
    detect_f<<<1, 64, 0, stream>>>((const unsigned short*)emb, flag);
    wtab_kernel<<<1, 320, 0, stream>>>(emb, W_w, W_b, flag, wtab);
    rnn_kernel<<<256, 256, 0, stream>>>(x, flag, wtab, U_w, head_w, head_b,
                                        (float*)d_out);
}

// Round 12
// 252.279 us; speedup vs baseline: 18.7649x; 1.7880x over previous
//
#include <hip/hip_runtime.h>
#include <cmath>

#define DIM 16
#define VOCAB 18
#define TLEN 2048
#define NBLK (TLEN / 64)

// Load float input element idx, from either a bf16 or f32 device buffer.
__device__ __forceinline__ float ldf(const void* p, int idx, int isbf) {
    if (isbf) {
        unsigned int w = ((const unsigned short*)p)[idx];
        return __uint_as_float(w << 16);
    }
    return ((const float*)p)[idx];
}

// ---------------------------------------------------------------------------
// Detector 1: token width. int64 tokens (0..17) have all odd 32-bit words 0.
// flag[0] <- 1 if int64, 0 if int32.
// ---------------------------------------------------------------------------
__global__ void detect_tok(const int* __restrict__ x32, int* __restrict__ flag) {
    int v = 0;
    for (int j = threadIdx.x; j < 4096; j += 64) v |= x32[2 * j + 1];
    unsigned long long any = __ballot(v != 0);
    if (threadIdx.x == 0) flag[0] = (any == 0ULL) ? 1 : 0;
}

// ---------------------------------------------------------------------------
// Detector 2: float width. bf16 words of N(0,1) data have exponent in
// [90,140]; f32 lo-mantissa words are uniform random -> certain failure.
// flag[1] <- 1 if bf16, 0 if f32.
// ---------------------------------------------------------------------------
__global__ void detect_f(const unsigned short* __restrict__ emb16,
                         int* __restrict__ flag) {
    int bad = 0;
    for (int j = threadIdx.x; j < VOCAB * DIM; j += 64) {
        unsigned short w = emb16[j];
        int e = (w >> 7) & 0xFF;
        if (!((e >= 90 && e <= 140) || (w & 0x7FFF) == 0)) bad = 1;
    }
    unsigned long long anybad = __ballot(bad);
    if (threadIdx.x == 0) flag[1] = (anybad == 0ULL) ? 1 : 0;
}

// ---------------------------------------------------------------------------
// Setup: wtab[v][k] = sum_d emb[v,d] * W_w[k,d] + W_b[k]   (18 x 16, f32)
// ---------------------------------------------------------------------------
__global__ void wtab_kernel(const void* __restrict__ emb,
                            const void* __restrict__ W_w,
                            const void* __restrict__ W_b,
                            const int* __restrict__ flag,
                            float* __restrict__ wtab) {
    int tid = threadIdx.x;
    int isbf = flag[1];
    if (tid < VOCAB * DIM) {
        int v = tid >> 4, kk = tid & 15;
        float s = ldf(W_b, kk, isbf);
#pragma unroll
        for (int d = 0; d < DIM; ++d)
            s = fmaf(ldf(emb, v * DIM + d, isbf), ldf(W_w, kk * DIM + d, isbf), s);
        wtab[tid] = s;
    }
}

// DPP row-rotate (within 16-lane rows), compile-time control.
template <int CTRL>
__device__ __forceinline__ float ror_f(float v) {
    return __int_as_float(
        __builtin_amdgcn_mov_dpp(__float_as_int(v), CTRL, 0xF, 0xF, true));
}

// tanh(x) = 1 - 2/(e^{2x}+1); exp2-based, saturates correctly at +-inf.
__device__ __forceinline__ float fast_tanh(float xx) {
    float e2 = __builtin_amdgcn_exp2f(xx * 2.8853900817779268f); // 2*log2(e)
    float r = __builtin_amdgcn_rcpf(e2 + 1.0f);
    return fmaf(-2.0f, r, 1.0f);
}

// ---------------------------------------------------------------------------
// Main RNN kernel. 16 lanes per batch element (lane k owns output dim k),
// 4 elements per wave, 4 waves per block, 256 blocks -> 4096 elements.
// h distribution: depth-4 DPP row_ror tree (no LDS pipe on critical path);
// U pre-rotated per-lane with runtime-probed rotation direction.
// ---------------------------------------------------------------------------
__global__ __launch_bounds__(256) void rnn_kernel(const int* __restrict__ x32,
                                                  const int* __restrict__ flag,
                                                  const float* __restrict__ wtab_g,
                                                  const void* __restrict__ U_w,
                                                  const void* __restrict__ head_w,
                                                  const void* __restrict__ head_b,
                                                  float* __restrict__ out) {
    __shared__ float lds_wtab[VOCAB * DIM];
    __shared__ float sU[DIM * DIM];
    __shared__ float lds_h[16][DIM];
    __shared__ int lds_tok[16][68];  // 68: int4-alignment-preserving bank pad

    const int tid = threadIdx.x;
    const int is64 = __builtin_amdgcn_readfirstlane(flag[0]);
    const int isbf = __builtin_amdgcn_readfirstlane(flag[1]);

    // Strided fills (NEVER the guarded-single-store 288>256 bug again).
    for (int i = tid; i < VOCAB * DIM; i += 256) lds_wtab[i] = wtab_g[i];
    for (int i = tid; i < DIM * DIM; i += 256) sU[i] = ldf(U_w, i, isbf);
    __syncthreads();

    const int lane = tid & 63;
    const int wave = tid >> 6;
    const int sub = lane >> 4;        // element within wave
    const int k = lane & 15;          // output dim owned by this lane
    const int e = (wave << 2) | sub;  // element within block

    // Probe DPP ror direction: after one ror:1, lane k holds lid of lane
    // (k+c)&15. Rotation j (composed) delivers h[(k + j*c) & 15].
    int p = __builtin_amdgcn_mov_dpp(k, 0x121, 0xF, 0xF, true);
    int c = (p - k) & 15;

    // Pre-rotated U: ur[j] = U[k][(k + j*c) & 15]  (register array).
    float ur[16];
#pragma unroll
    for (int j = 0; j < 16; ++j) ur[j] = sU[(k << 4) | ((k + j * c) & 15)];

    float h = 0.0f;

    for (int blk = 0; blk < NBLK; ++blk) {
        __syncthreads();  // lds_tok safe to refill
        for (int i = tid; i < 1024; i += 256) {
            int ee = i >> 6, s = i & 63;
            size_t idx = (size_t)((blockIdx.x << 4) | ee) * TLEN + (blk << 6) + s;
            lds_tok[ee][s] = is64 ? x32[idx << 1] : x32[idx];
        }
        __syncthreads();

        float w = lds_wtab[(lds_tok[e][0] << 4) | k];  // wtab[tok][k], step 0
#pragma unroll 4
        for (int s = 0; s < 64; ++s) {
            // Prefetch next step's wtab value (h-independent chain).
            float wn = (s < 63) ? lds_wtab[(lds_tok[e][s + 1] << 4) | k] : 0.0f;

            float r0 = h;
            float r1 = ror_f<0x121>(r0);   // ror:1
            float r2 = ror_f<0x122>(r0);   // ror:2
            float r3 = ror_f<0x122>(r1);
            float r4 = ror_f<0x124>(r0);   // ror:4
            float r5 = ror_f<0x124>(r1);
            float r6 = ror_f<0x124>(r2);
            float r7 = ror_f<0x124>(r3);
            float r8 = ror_f<0x128>(r0);   // ror:8
            float r9 = ror_f<0x128>(r1);
            float r10 = ror_f<0x128>(r2);
            float r11 = ror_f<0x128>(r3);
            float r12 = ror_f<0x128>(r4);
            float r13 = ror_f<0x128>(r5);
            float r14 = ror_f<0x128>(r6);
            float r15 = ror_f<0x128>(r7);

            float a0 = fmaf(ur[0], r0, w);
            float a1 = ur[1] * r1;
            float a2 = ur[2] * r2;
            float a3 = ur[3] * r3;
            a0 = fmaf(ur[4], r4, a0);
            a1 = fmaf(ur[5], r5, a1);
            a2 = fmaf(ur[6], r6, a2);
            a3 = fmaf(ur[7], r7, a3);
            a0 = fmaf(ur[8], r8, a0);
            a1 = fmaf(ur[9], r9, a1);
            a2 = fmaf(ur[10], r10, a2);
            a3 = fmaf(ur[11], r11, a3);
            a0 = fmaf(ur[12], r12, a0);
            a1 = fmaf(ur[13], r13, a1);
            a2 = fmaf(ur[14], r14, a2);
            a3 = fmaf(ur[15], r15, a3);

            h = fast_tanh((a0 + a1) + (a2 + a3));
            w = wn;
        }
    }

    // Head: out[b,v] = h . head_w[v,:] + head_b[v], f32 store.
    lds_h[e][k] = h;
    __syncthreads();

    for (int i = tid; i < 16 * VOCAB; i += 256) {
        int ee = i / VOCAB;
        int v = i - ee * VOCAB;
        float s = ldf(head_b, v, isbf);
#pragma unroll
        for (int d = 0; d < DIM; ++d)
            s = fmaf(lds_h[ee][d], ldf(head_w, (v << 4) + d, isbf), s);
        out[(size_t)((blockIdx.x << 4) | ee) * VOCAB + v] = s;
    }
}

extern "C" void kernel_launch(void* const* d_in, const int* in_sizes, int n_in,
                              void* d_out, int out_size, void* d_ws, size_t ws_size,
                              hipStream_t stream) {
    const int* x = (const int*)d_in[0];
    const void* emb = d_in[1];
    const void* W_w = d_in[2];
    const void* W_b = d_in[3];
    const void* U_w = d_in[4];
    const void* head_w = d_in[5];
    const void* head_b = d_in[6];

    float* wtab = (float*)d_ws;              // 288 floats
    int* flag = (int*)((char*)d_ws + 4096);  // [0]=tok is64, [1]=floats are bf16

    detect_tok<<<1, 64, 0, stream>>>(x, flag);
    detect_f<<<1, 64, 0, stream>>>((const unsigned short*)emb, flag);
    wtab_kernel<<<1, 320, 0, stream>>>(emb, W_w, W_b, flag, wtab);
    rnn_kernel<<<256, 256, 0, stream>>>(x, flag, wtab, U_w, head_w, head_b,
                                        (float*)d_out);
}

// Round 13
// 217.483 us; speedup vs baseline: 21.7671x; 1.1600x over previous
//
#include <hip/hip_runtime.h>
#include <cmath>

#define DIM 16
#define VOCAB 18
#define TLEN 2048
#define NBLK (TLEN / 64)
#define WPAD 17  // padded wtab row stride (bank spread)

// Load float input element idx, from either a bf16 or f32 device buffer.
__device__ __forceinline__ float ldf(const void* p, int idx, int isbf) {
    if (isbf) {
        unsigned int w = ((const unsigned short*)p)[idx];
        return __uint_as_float(w << 16);
    }
    return ((const float*)p)[idx];
}

// ---------------------------------------------------------------------------
// Detector 1: token width. int64 tokens (0..17) have all odd 32-bit words 0.
// flag[0] <- 1 if int64, 0 if int32.
// ---------------------------------------------------------------------------
__global__ void detect_tok(const int* __restrict__ x32, int* __restrict__ flag) {
    int v = 0;
    for (int j = threadIdx.x; j < 4096; j += 64) v |= x32[2 * j + 1];
    unsigned long long any = __ballot(v != 0);
    if (threadIdx.x == 0) flag[0] = (any == 0ULL) ? 1 : 0;
}

// ---------------------------------------------------------------------------
// Detector 2: float width. bf16 words of N(0,1) data have exponent in
// [90,140]; f32 lo-mantissa words are uniform random -> certain failure.
// flag[1] <- 1 if bf16, 0 if f32.
// ---------------------------------------------------------------------------
__global__ void detect_f(const unsigned short* __restrict__ emb16,
                         int* __restrict__ flag) {
    int bad = 0;
    for (int j = threadIdx.x; j < VOCAB * DIM; j += 64) {
        unsigned short w = emb16[j];
        int e = (w >> 7) & 0xFF;
        if (!((e >= 90 && e <= 140) || (w & 0x7FFF) == 0)) bad = 1;
    }
    unsigned long long anybad = __ballot(bad);
    if (threadIdx.x == 0) flag[1] = (anybad == 0ULL) ? 1 : 0;
}

// ---------------------------------------------------------------------------
// Setup: wtab[v][k] = sum_d emb[v,d] * W_w[k,d] + W_b[k]   (18 x 16, f32)
// ---------------------------------------------------------------------------
__global__ void wtab_kernel(const void* __restrict__ emb,
                            const void* __restrict__ W_w,
                            const void* __restrict__ W_b,
                            const int* __restrict__ flag,
                            float* __restrict__ wtab) {
    int tid = threadIdx.x;
    int isbf = flag[1];
    if (tid < VOCAB * DIM) {
        int v = tid >> 4, kk = tid & 15;
        float s = ldf(W_b, kk, isbf);
#pragma unroll
        for (int d = 0; d < DIM; ++d)
            s = fmaf(ldf(emb, v * DIM + d, isbf), ldf(W_w, kk * DIM + d, isbf), s);
        wtab[tid] = s;
    }
}

// DPP row-rotate (within 16-lane rows), compile-time control 0x120|N.
template <int CTRL>
__device__ __forceinline__ float ror_f(float v) {
    return __int_as_float(
        __builtin_amdgcn_mov_dpp(__float_as_int(v), CTRL, 0xF, 0xF, true));
}

#define TWO_LOG2E 2.8853900817779268f  // 2*log2(e)

// tanh from a pre-scaled argument S = 2*log2(e)*x:
// tanh(x) = 1 - 2/(2^S + 1).  Saturates correctly at +-inf.
__device__ __forceinline__ float tanh_scaled(float S) {
    float e2 = __builtin_amdgcn_exp2f(S);
    float r = __builtin_amdgcn_rcpf(e2 + 1.0f);
    return fmaf(-2.0f, r, 1.0f);
}

// ---------------------------------------------------------------------------
// Main RNN kernel. 16 lanes per batch element (lane k owns output dim k),
// 4 elements per wave, 4 waves per block, 256 blocks -> 4096 elements.
// h distribution: flat depth-1 DPP row_ror:j, j=1..15; U pre-rotated per lane
// (direction runtime-probed). wtab/U pre-scaled by 2*log2(e). Tokens double-
// buffered in LDS; 2-stage software pipeline on the token->wtab read chain.
// ---------------------------------------------------------------------------
__global__ __launch_bounds__(256) void rnn_kernel(const int* __restrict__ x32,
                                                  const int* __restrict__ flag,
                                                  const float* __restrict__ wtab_g,
                                                  const void* __restrict__ U_w,
                                                  const void* __restrict__ head_w,
                                                  const void* __restrict__ head_b,
                                                  float* __restrict__ out) {
    __shared__ float lds_wtab[VOCAB * WPAD];
    __shared__ float sU[DIM * DIM];
    __shared__ float lds_h[16][DIM];
    __shared__ int lds_tok[2][16][68];

    const int tid = threadIdx.x;
    const int is64 = __builtin_amdgcn_readfirstlane(flag[0]);
    const int isbf = __builtin_amdgcn_readfirstlane(flag[1]);

    // Strided fills (never the guarded-single-store 288>256 bug again).
    // wtab staged pre-scaled by 2*log2(e), padded row stride 17.
    for (int i = tid; i < VOCAB * DIM; i += 256)
        lds_wtab[(i >> 4) * WPAD + (i & 15)] = wtab_g[i] * TWO_LOG2E;
    for (int i = tid; i < DIM * DIM; i += 256) sU[i] = ldf(U_w, i, isbf);

    const int lane = tid & 63;
    const int wave = tid >> 6;
    const int sub = lane >> 4;        // element within wave
    const int k = lane & 15;          // output dim owned by this lane
    const int e = (wave << 2) | sub;  // element within block

    // Probe DPP ror direction: after ror:1, lane k holds id of lane (k+c)&15.
    // All row_ror:j share direction => ror:j delivers h[(k + j*c) & 15].
    int p = __builtin_amdgcn_mov_dpp(k, 0x121, 0xF, 0xF, true);
    int c = (p - k) & 15;

#define STAGE(B, BUF)                                                            \
    for (int i = tid; i < 1024; i += 256) {                                      \
        int ee = i >> 6, s = i & 63;                                             \
        size_t idx = (size_t)((blockIdx.x << 4) | ee) * TLEN + ((B) << 6) + s;   \
        lds_tok[BUF][ee][s] = is64 ? x32[idx << 1] : x32[idx];                   \
    }

    STAGE(0, 0)
    __syncthreads();  // covers lds_wtab/sU fills and block-0 tokens

    // Pre-rotated, pre-scaled U: ur[j] = 2log2e * U[k][(k + j*c) & 15].
    float ur[16];
#pragma unroll
    for (int j = 0; j < 16; ++j)
        ur[j] = sU[(k << 4) | ((k + j * c) & 15)] * TWO_LOG2E;

    float h = 0.0f;

    for (int blk = 0; blk < NBLK; ++blk) {
        const int cb = blk & 1, nb = cb ^ 1;
        if (blk + 1 < NBLK) {
            STAGE(blk + 1, nb)
        }
        __syncthreads();  // next-blk tokens staged; prev readers done

        const int(*cur)[68] = lds_tok[cb];
        const int(*nxt)[68] = lds_tok[nb];

        // 2-stage pipeline: t1 = token for step s+1, w = wtab val for step s.
        int t1 = cur[e][1];
        float w = lds_wtab[cur[e][0] * WPAD + k];

#pragma unroll
        for (int s = 0; s < 64; ++s) {
            float wn = lds_wtab[t1 * WPAD + k];                      // for s+1
            int t2 = (s < 62) ? cur[e][s + 2] : nxt[e][s - 62];      // for s+2

            float r1 = ror_f<0x121>(h);
            float r2 = ror_f<0x122>(h);
            float r3 = ror_f<0x123>(h);
            float r4 = ror_f<0x124>(h);
            float r5 = ror_f<0x125>(h);
            float r6 = ror_f<0x126>(h);
            float r7 = ror_f<0x127>(h);
            float r8 = ror_f<0x128>(h);
            float r9 = ror_f<0x129>(h);
            float r10 = ror_f<0x12A>(h);
            float r11 = ror_f<0x12B>(h);
            float r12 = ror_f<0x12C>(h);
            float r13 = ror_f<0x12D>(h);
            float r14 = ror_f<0x12E>(h);
            float r15 = ror_f<0x12F>(h);

            float a0 = fmaf(ur[0], h, w);
            float a1 = ur[1] * r1;
            float a2 = ur[2] * r2;
            float a3 = ur[3] * r3;
            a0 = fmaf(ur[4], r4, a0);
            a1 = fmaf(ur[5], r5, a1);
            a2 = fmaf(ur[6], r6, a2);
            a3 = fmaf(ur[7], r7, a3);
            a0 = fmaf(ur[8], r8, a0);
            a1 = fmaf(ur[9], r9, a1);
            a2 = fmaf(ur[10], r10, a2);
            a3 = fmaf(ur[11], r11, a3);
            a0 = fmaf(ur[12], r12, a0);
            a1 = fmaf(ur[13], r13, a1);
            a2 = fmaf(ur[14], r14, a2);
            a3 = fmaf(ur[15], r15, a3);

            h = tanh_scaled((a0 + a1) + (a2 + a3));
            w = wn;
            t1 = t2;
        }
        __syncthreads();  // readers of cur done before it is restaged
    }

    // Head: out[b,v] = h . head_w[v,:] + head_b[v], f32 store.
    lds_h[e][k] = h;
    __syncthreads();

    for (int i = tid; i < 16 * VOCAB; i += 256) {
        int ee = i / VOCAB;
        int v = i - ee * VOCAB;
        float s = ldf(head_b, v, isbf);
#pragma unroll
        for (int d = 0; d < DIM; ++d)
            s = fmaf(lds_h[ee][d], ldf(head_w, (v << 4) + d, isbf), s);
        out[(size_t)((blockIdx.x << 4) | ee) * VOCAB + v] = s;
    }
}

extern "C" void kernel_launch(void* const* d_in, const int* in_sizes, int n_in,
                              void* d_out, int out_size, void* d_ws, size_t ws_size,
                              hipStream_t stream) {
    const int* x = (const int*)d_in[0];
    const void* emb = d_in[1];
    const void* W_w = d_in[2];
    const void* W_b = d_in[3];
    const void* U_w = d_in[4];
    const void* head_w = d_in[5];
    const void* head_b = d_in[6];

    float* wtab = (float*)d_ws;              // 288 floats
    int* flag = (int*)((char*)d_ws + 4096);  // [0]=tok is64, [1]=floats are bf16

    detect_tok<<<1, 64, 0, stream>>>(x, flag);
    detect_f<<<1, 64, 0, stream>>>((const unsigned short*)emb, flag);
    wtab_kernel<<<1, 320, 0, stream>>>(emb, W_w, W_b, flag, wtab);
    rnn_kernel<<<256, 256, 0, stream>>>(x, flag, wtab, U_w, head_w, head_b,
                                        (float*)d_out);
}